// Round 14
// baseline (119.123 us; speedup 1.0000x reference)
//
#include <hip/hip_runtime.h>
#include <math.h>

#define B_DIM  48
#define S_DIM  96
#define D_DIM  54
#define DENC   4
#define DVAR   8
#define NFLAT  (B_DIM * S_DIM)   // 4608

// One complex amplitude = one 32-bit reg: (x=re in lo16, y=im in hi16), f16.
typedef _Float16 h2 __attribute__((ext_vector_type(2)));

__device__ __forceinline__ int h2i(h2 v) { return __builtin_bit_cast(int, v); }
__device__ __forceinline__ h2  i2h(int v) { return __builtin_bit_cast(h2, v); }

// Forced packed-f16 math (VOP3P) — R13-validated.
__device__ __forceinline__ int pk_mul(int a, int b) {
    int d;
    asm("v_pk_mul_f16 %0, %1, %2" : "=v"(d) : "v"(a), "v"(b));
    return d;
}
__device__ __forceinline__ int pk_fma(int a, int b, int c) {
    int d;
    asm("v_pk_fma_f16 %0, %1, %2, %3" : "=v"(d) : "v"(a), "v"(b), "v"(c));
    return d;
}

// Lane-xor primitives on 32-bit patterns — R5/R8/R11/R13 hardware-validated set.
template<int LM>
__device__ __forceinline__ int lxi(int x, int lane) {
    if constexpr (LM == 1)       return __builtin_amdgcn_update_dpp(x, x, 0xB1, 0xF, 0xF, true);  // quad[1,0,3,2]
    else if constexpr (LM == 2)  return __builtin_amdgcn_update_dpp(x, x, 0x4E, 0xF, 0xF, true);  // quad[2,3,0,1]
    else if constexpr (LM == 4)  return __builtin_amdgcn_ds_swizzle(x, 0x101F);                   // xor4
    else if constexpr (LM == 8)  return __builtin_amdgcn_update_dpp(x, x, 0x128, 0xF, 0xF, true); // ROW_ROR:8
    else if constexpr (LM == 16) return __builtin_amdgcn_ds_swizzle(x, 0x401F);                   // xor16
    else {
        auto r = __builtin_amdgcn_permlane32_swap(x, x, false, false);
        // ret[0] = [lo,lo], ret[1] = [hi,hi]; want [hi,lo]
        return (lane & 32) ? r[0] : r[1];
    }
}
template<int LM>
__device__ __forceinline__ float lx(float v, int lane) {
    return __int_as_float(lxi<LM>(__float_as_int(v), lane));
}

__device__ __forceinline__ float wave_sum(float v, int lane) {
    v += lx<32>(v, lane);
    v += lx<16>(v, lane);
    v += lx<8>(v, lane);
    v += lx<4>(v, lane);
    v += lx<2>(v, lane);
    v += lx<1>(v, lane);
    return v;
}

// State layout: amp index i (9 bits) -> lane = i>>3 (bits 8..3), reg r = i&7 (bits 2..0).
// Qubit j <-> state bit BJ = 8-j.

// halves-swap (y,x) <- (x,y): one v_alignbit
__device__ __forceinline__ int hswapi(int p) {
    return __builtin_amdgcn_alignbit(p, p, 16);
}

// CNOT ring (control j, target (j+1)%9): stages (8,7)..(4,3) = Gray-code lane
// permutation dst L <- src L^(L>>1), ONE ds_bpermute per amplitude (R8-validated),
// then reg-local fixups + xor32 stage.
__device__ __forceinline__ void ring(h2 st[8], int lane) {
    const int gray = (lane ^ (lane >> 1)) << 2;
#pragma unroll
    for (int r = 0; r < 8; ++r)
        st[r] = i2h(__builtin_amdgcn_ds_bpermute(gray, h2i(st[r])));
    // (3,2): ctrl lane bit0 (b3), tgt reg bit2
    {
        const bool c0 = (lane & 1) != 0;
#pragma unroll
        for (int r = 0; r < 4; ++r) {
            h2 a = st[r], b = st[r + 4];
            st[r]     = c0 ? b : a;
            st[r + 4] = c0 ? a : b;
        }
    }
    // (2,1): regs with bit2: r <-> r^2 (rename)
    { h2 t = st[4]; st[4] = st[6]; st[6] = t; }
    { h2 t = st[5]; st[5] = st[7]; st[7] = t; }
    // (1,0): regs with bit1: r <-> r^1 (rename)
    { h2 t = st[2]; st[2] = st[3]; st[3] = t; }
    { h2 t = st[6]; st[6] = st[7]; st[7] = t; }
    // (0,8): odd regs: xor32
#pragma unroll
    for (int r = 1; r < 8; r += 2)
        st[r] = i2h(lxi<32>(h2i(st[r]), lane));
}

// RY(theta): n0 = c*a0 - s*a1 ; n1 = s*a0 + c*a1.  c2i=(c,c), s2i=(s,s) packed f16.
template<int BJ>
__device__ __forceinline__ void rot_ry(h2 st[8], int c2i, int s2i, int lane) {
    if constexpr (BJ >= 3) {
        constexpr int lm = 1 << (BJ - 3);
        const int sg = (lane & lm) ? s2i : (s2i ^ 0x80008000); // side1:+s, side0:-s
#pragma unroll
        for (int r = 0; r < 8; ++r) {
            int p = lxi<lm>(h2i(st[r]), lane);
            st[r] = i2h(pk_fma(p, sg, pk_mul(h2i(st[r]), c2i)));
        }
    } else {
        constexpr int M = 1 << BJ;
        const int ns2 = s2i ^ 0x80008000;
#pragma unroll
        for (int r = 0; r < 8; ++r) {
            if ((r & M) == 0) {
                int a = h2i(st[r]), b = h2i(st[r + M]);
                st[r]     = i2h(pk_fma(b, ns2, pk_mul(a, c2i)));
                st[r + M] = i2h(pk_fma(a, s2i, pk_mul(b, c2i)));
            }
        }
    }
}

// RX(theta): n = c*a + (s,-s)*hswap(partner) — R11-validated form.
template<int BJ>
__device__ __forceinline__ void rot_rx(h2 st[8], int c2i, int s2i, int lane) {
    const int sm = s2i ^ 0x80000000;   // (s, -s)
    if constexpr (BJ >= 3) {
        constexpr int lm = 1 << (BJ - 3);
#pragma unroll
        for (int r = 0; r < 8; ++r) {
            int p = lxi<lm>(h2i(st[r]), lane);
            st[r] = i2h(pk_fma(hswapi(p), sm, pk_mul(h2i(st[r]), c2i)));
        }
    } else {
        constexpr int M = 1 << BJ;
#pragma unroll
        for (int r = 0; r < 8; ++r) {
            if ((r & M) == 0) {
                int a = h2i(st[r]), b = h2i(st[r + M]);
                st[r]     = i2h(pk_fma(hswapi(b), sm, pk_mul(a, c2i)));
                st[r + M] = i2h(pk_fma(hswapi(a), sm, pk_mul(b, c2i)));
            }
        }
    }
}

#define INITQ(j) { rot_rx<8 - (j)>(st, cc[2 * (j)],     ss[2 * (j)],     lane);  \
                   rot_ry<8 - (j)>(st, cc[2 * (j) + 1], ss[2 * (j) + 1], lane); }

// cc/ss: per-angle packed (c,c) and (s,s) tables for this circuit segment.
__device__ __forceinline__ void run_circuit(h2 st[8], const int* cc, const int* ss,
                                            int layers, int lane) {
    INITQ(0) INITQ(1) INITQ(2) INITQ(3) INITQ(4)
    INITQ(5) INITQ(6) INITQ(7) INITQ(8)
    const int* pc = cc + 18;
    const int* ps = ss + 18;
#pragma unroll 1
    for (int L = 0; L < layers; ++L) {
        ring(st, lane);
        rot_ry<8>(st, pc[0], ps[0], lane);
        rot_ry<7>(st, pc[1], ps[1], lane);
        rot_ry<6>(st, pc[2], ps[2], lane);
        rot_ry<5>(st, pc[3], ps[3], lane);
        rot_ry<4>(st, pc[4], ps[4], lane);
        rot_ry<3>(st, pc[5], ps[5], lane);
        rot_ry<2>(st, pc[6], ps[6], lane);
        rot_ry<1>(st, pc[7], ps[7], lane);
        rot_ry<0>(st, pc[8], ps[8], lane);
        pc += 9; ps += 9;
    }
}

// <Z>, <X>, <Y> on qubit with state-bit BJ (f32 accumulation) — R11-validated.
template<int BJ>
__device__ __forceinline__ void expv(const h2 st[8], int lane, float& ez, float& ex, float& ey) {
    ez = ex = ey = 0.f;
    if constexpr (BJ >= 3) {
        constexpr int lm = 1 << (BJ - 3);
        const float sgn = (lane & lm) ? -1.f : 1.f;
#pragma unroll
        for (int r = 0; r < 8; ++r) {
            h2 p = i2h(lxi<lm>(h2i(st[r]), lane));
            float x = (float)st[r].x, y = (float)st[r].y;
            float px = (float)p.x,   py = (float)p.y;
            ez += sgn * (x * x + y * y);
            ex += x * px + y * py;            // both halves -> 2*Re total
            ey += sgn * (x * py - y * px);    // both halves -> 2*Im total
        }
    } else {
        constexpr int M = 1 << BJ;
#pragma unroll
        for (int r = 0; r < 8; ++r) {
            if ((r & M) == 0) {
                float ax = (float)st[r].x,     ay = (float)st[r].y;
                float bx = (float)st[r + M].x, by = (float)st[r + M].y;
                ez += (ax * ax + ay * ay) - (bx * bx + by * by);
                ex += 2.f * (ax * bx + ay * by);
                ey += 2.f * (ax * by - ay * bx);
            }
        }
    }
    ez = wave_sum(ez, lane); ex = wave_sum(ex, lane); ey = wave_sum(ey, lane);
}

// One wave per (input, circuit): cid 0=Q, 1=K, 2=V. 13824 waves = 13.5/SIMD.
__global__ __launch_bounds__(64) void sim_kernel(
    const float* __restrict__ inp, const float* __restrict__ wq,
    const float* __restrict__ wk,  const float* __restrict__ wv,
    float* __restrict__ outQ, float* __restrict__ outK, float* __restrict__ outV)
{
    __shared__ int csc[144];   // packed (c,c): enc 54 + this circuit's 90
    __shared__ int css[144];   // packed (s,s)

    const int lane = threadIdx.x;
    const int gbl  = blockIdx.x;
    const int cid  = gbl % 3;            // 0=Q 1=K 2=V
    const int fi   = gbl / 3;            // flat = s*B + b
    const int b = fi % B_DIM, s = fi / B_DIM;
    const float* x = inp + ((size_t)b * S_DIM + s) * D_DIM;
    const float* w = (cid == 0) ? wq : (cid == 1) ? wk : wv;

    for (int k = lane; k < 144; k += 64) {
        float ang = (k < 54) ? x[k] : w[k - 54];
        float sn, cn; sincosf(0.5f * ang, &sn, &cn);
        _Float16 hc = (_Float16)cn, hs = (_Float16)sn;
        h2 c2 = {hc, hc}, s2 = {hs, hs};
        csc[k] = h2i(c2);
        css[k] = h2i(s2);
    }
    // single wave: LDS write->read ordering handled by lgkmcnt, no barrier needed

    h2 st[8];
#pragma unroll
    for (int r = 0; r < 8; ++r) st[r] = i2h(0);
    if (lane == 0) { h2 one = {(_Float16)1.f, (_Float16)0.f}; st[0] = one; }

    run_circuit(st, csc, css, DENC, lane);        // encoding
    run_circuit(st, csc + 54, css + 54, DVAR, lane); // this head's variational circuit

    if (cid < 2) {
        float p = 0.f;
#pragma unroll
        for (int r = 0; r < 8; ++r) {
            float xx = (float)st[r].x, yy = (float)st[r].y;
            p += xx * xx + yy * yy;
        }
        p = (lane & 32) ? -p : p;     // qubit 0 = state bit 8 = lane bit 5
        p = wave_sum(p, lane);
        if (lane == 0) { if (cid == 0) outQ[fi] = p; else outK[fi] = p; }
    } else {
        float* vrow = outV + (size_t)fi * D_DIM;
#define EXPQ(q) { float ez, ex, ey; expv<8 - (q)>(st, lane, ez, ex, ey);            \
                  if (lane == 0) { vrow[(q)] = ez; vrow[9 + (q)] = ex;              \
                                   vrow[18 + (q)] = ey; vrow[27 + (q)] = ez;        \
                                   vrow[36 + (q)] = ex; vrow[45 + (q)] = ey; } }
        EXPQ(0) EXPQ(1) EXPQ(2) EXPQ(3) EXPQ(4)
        EXPQ(5) EXPQ(6) EXPQ(7) EXPQ(8)
#undef EXPQ
    }
}

__global__ __launch_bounds__(256) void attn_kernel(
    const float* __restrict__ inp, const float* __restrict__ Q,
    const float* __restrict__ K,   const float* __restrict__ V,
    float* __restrict__ out)
{
    __shared__ float w4[4][S_DIM];
    const int warp = threadIdx.x >> 6;
    const int t    = threadIdx.x & 63;
    const int bi   = blockIdx.x * 4 + warp;   // b*S + i
    const int b    = bi / S_DIM;
    const int i    = bi % S_DIM;
    float* w = w4[warp];

    const float q = Q[i * B_DIM + b];
    float e0, e1 = 0.f;
    {
        float d0 = q - K[t * B_DIM + b];
        e0 = expf(-d0 * d0);
        w[t] = e0;
        if (t < S_DIM - 64) {
            float d1 = q - K[(t + 64) * B_DIM + b];
            e1 = expf(-d1 * d1);
            w[t + 64] = e1;
        }
    }
    float ps = wave_sum(e0 + e1, t);
    const float inv = 1.f / ps;

    if (t < D_DIM) {
        float acc = 0.f;
        for (int j = 0; j < S_DIM; ++j)
            acc += w[j] * V[(size_t)(j * B_DIM + b) * D_DIM + t];
        size_t o = (size_t)bi * D_DIM + t;
        out[o] = inp[o] + acc * inv;
    }
}

extern "C" void kernel_launch(void* const* d_in, const int* in_sizes, int n_in,
                              void* d_out, int out_size, void* d_ws, size_t ws_size,
                              hipStream_t stream)
{
    (void)in_sizes; (void)n_in; (void)out_size; (void)ws_size;
    const float* inp = (const float*)d_in[0];
    const float* wq  = (const float*)d_in[1];
    const float* wk  = (const float*)d_in[2];
    const float* wv  = (const float*)d_in[3];
    float* outp = (float*)d_out;

    float* Qw = (float*)d_ws;
    float* Kw = Qw + NFLAT;
    float* Vw = Kw + NFLAT;

    sim_kernel<<<NFLAT * 3, 64, 0, stream>>>(inp, wq, wk, wv, Qw, Kw, Vw);
    attn_kernel<<<NFLAT / 4, 256, 0, stream>>>(inp, Qw, Kw, Vw, outp);
}

// Round 15
// 108.787 us; speedup vs baseline: 1.0950x; 1.0950x over previous
//
#include <hip/hip_runtime.h>
#include <math.h>

#define B_DIM  48
#define S_DIM  96
#define D_DIM  54
#define DENC   4
#define DVAR   8
#define NFLAT  (B_DIM * S_DIM)   // 4608

// One complex amplitude = one 32-bit reg: (x=re in lo16, y=im in hi16), f16.
typedef _Float16 h2 __attribute__((ext_vector_type(2)));

__device__ __forceinline__ int h2i(h2 v) { return __builtin_bit_cast(int, v); }
__device__ __forceinline__ h2  i2h(int v) { return __builtin_bit_cast(h2, v); }

// Forced packed-f16 math (VOP3P) — R13-validated.
__device__ __forceinline__ int pk_mul(int a, int b) {
    int d;
    asm("v_pk_mul_f16 %0, %1, %2" : "=v"(d) : "v"(a), "v"(b));
    return d;
}
__device__ __forceinline__ int pk_fma(int a, int b, int c) {
    int d;
    asm("v_pk_fma_f16 %0, %1, %2, %3" : "=v"(d) : "v"(a), "v"(b), "v"(c));
    return d;
}

// Lane-xor primitives on 32-bit patterns — R5/R8/R11/R13 hardware-validated set.
template<int LM>
__device__ __forceinline__ int lxi(int x, int lane) {
    if constexpr (LM == 1)       return __builtin_amdgcn_update_dpp(x, x, 0xB1, 0xF, 0xF, true);  // quad[1,0,3,2]
    else if constexpr (LM == 2)  return __builtin_amdgcn_update_dpp(x, x, 0x4E, 0xF, 0xF, true);  // quad[2,3,0,1]
    else if constexpr (LM == 4)  return __builtin_amdgcn_ds_swizzle(x, 0x101F);                   // xor4
    else if constexpr (LM == 8)  return __builtin_amdgcn_update_dpp(x, x, 0x128, 0xF, 0xF, true); // ROW_ROR:8
    else if constexpr (LM == 16) return __builtin_amdgcn_ds_swizzle(x, 0x401F);                   // xor16
    else {
        auto r = __builtin_amdgcn_permlane32_swap(x, x, false, false);
        // ret[0] = [lo,lo], ret[1] = [hi,hi]; want [hi,lo]
        return (lane & 32) ? r[0] : r[1];
    }
}
template<int LM>
__device__ __forceinline__ float lx(float v, int lane) {
    return __int_as_float(lxi<LM>(__float_as_int(v), lane));
}

__device__ __forceinline__ float wave_sum(float v, int lane) {
    v += lx<32>(v, lane);
    v += lx<16>(v, lane);
    v += lx<8>(v, lane);
    v += lx<4>(v, lane);
    v += lx<2>(v, lane);
    v += lx<1>(v, lane);
    return v;
}

// State layout: amp index i (9 bits) -> lane = i>>3 (bits 8..3), reg r = i&7 (bits 2..0).
// Qubit j <-> state bit BJ = 8-j.

// halves-swap (y,x) <- (x,y): one v_alignbit
__device__ __forceinline__ int hswapi(int p) {
    return __builtin_amdgcn_alignbit(p, p, 16);
}

// CNOT ring (control j, target (j+1)%9): stages (8,7)..(4,3) = Gray-code lane
// permutation dst L <- src L^(L>>1), ONE ds_bpermute per amplitude (R8-validated),
// then reg-local fixups + xor32 stage.
__device__ __forceinline__ void ring(h2 st[8], int lane) {
    const int gray = (lane ^ (lane >> 1)) << 2;
#pragma unroll
    for (int r = 0; r < 8; ++r)
        st[r] = i2h(__builtin_amdgcn_ds_bpermute(gray, h2i(st[r])));
    // (3,2): ctrl lane bit0 (b3), tgt reg bit2
    {
        const bool c0 = (lane & 1) != 0;
#pragma unroll
        for (int r = 0; r < 4; ++r) {
            h2 a = st[r], b = st[r + 4];
            st[r]     = c0 ? b : a;
            st[r + 4] = c0 ? a : b;
        }
    }
    // (2,1): regs with bit2: r <-> r^2 (rename)
    { h2 t = st[4]; st[4] = st[6]; st[6] = t; }
    { h2 t = st[5]; st[5] = st[7]; st[7] = t; }
    // (1,0): regs with bit1: r <-> r^1 (rename)
    { h2 t = st[2]; st[2] = st[3]; st[3] = t; }
    { h2 t = st[6]; st[6] = st[7]; st[7] = t; }
    // (0,8): odd regs: xor32
#pragma unroll
    for (int r = 1; r < 8; r += 2)
        st[r] = i2h(lxi<32>(h2i(st[r]), lane));
}

// RY(theta): n0 = c*a0 - s*a1 ; n1 = s*a0 + c*a1.  c2i=(c,c), s2i=(s,s) packed f16.
template<int BJ>
__device__ __forceinline__ void rot_ry(h2 st[8], int c2i, int s2i, int lane) {
    if constexpr (BJ >= 3) {
        constexpr int lm = 1 << (BJ - 3);
        const int sg = (lane & lm) ? s2i : (s2i ^ 0x80008000); // side1:+s, side0:-s
#pragma unroll
        for (int r = 0; r < 8; ++r) {
            int p = lxi<lm>(h2i(st[r]), lane);
            st[r] = i2h(pk_fma(p, sg, pk_mul(h2i(st[r]), c2i)));
        }
    } else {
        constexpr int M = 1 << BJ;
        const int ns2 = s2i ^ 0x80008000;
#pragma unroll
        for (int r = 0; r < 8; ++r) {
            if ((r & M) == 0) {
                int a = h2i(st[r]), b = h2i(st[r + M]);
                st[r]     = i2h(pk_fma(b, ns2, pk_mul(a, c2i)));
                st[r + M] = i2h(pk_fma(a, s2i, pk_mul(b, c2i)));
            }
        }
    }
}

// RX(theta): n = c*a + (s,-s)*hswap(partner) — R11-validated form.
template<int BJ>
__device__ __forceinline__ void rot_rx(h2 st[8], int c2i, int s2i, int lane) {
    const int sm = s2i ^ 0x80000000;   // (s, -s)
    if constexpr (BJ >= 3) {
        constexpr int lm = 1 << (BJ - 3);
#pragma unroll
        for (int r = 0; r < 8; ++r) {
            int p = lxi<lm>(h2i(st[r]), lane);
            st[r] = i2h(pk_fma(hswapi(p), sm, pk_mul(h2i(st[r]), c2i)));
        }
    } else {
        constexpr int M = 1 << BJ;
#pragma unroll
        for (int r = 0; r < 8; ++r) {
            if ((r & M) == 0) {
                int a = h2i(st[r]), b = h2i(st[r + M]);
                st[r]     = i2h(pk_fma(hswapi(b), sm, pk_mul(a, c2i)));
                st[r + M] = i2h(pk_fma(hswapi(a), sm, pk_mul(b, c2i)));
            }
        }
    }
}

#define INITQ(j) { rot_rx<8 - (j)>(st, cc[2 * (j)],     ss[2 * (j)],     lane);  \
                   rot_ry<8 - (j)>(st, cc[2 * (j) + 1], ss[2 * (j) + 1], lane); }

__device__ __forceinline__ void ry_layer(h2 st[8], const int* pc, const int* ps, int lane) {
    rot_ry<8>(st, pc[0], ps[0], lane);
    rot_ry<7>(st, pc[1], ps[1], lane);
    rot_ry<6>(st, pc[2], ps[2], lane);
    rot_ry<5>(st, pc[3], ps[3], lane);
    rot_ry<4>(st, pc[4], ps[4], lane);
    rot_ry<3>(st, pc[5], ps[5], lane);
    rot_ry<2>(st, pc[6], ps[6], lane);
    rot_ry<1>(st, pc[7], ps[7], lane);
    rot_ry<0>(st, pc[8], ps[8], lane);
}

// <Z>, <X>, <Y> on qubit with state-bit BJ (f32 accumulation) — R11-validated.
template<int BJ>
__device__ __forceinline__ void expv(const h2 st[8], int lane, float& ez, float& ex, float& ey) {
    ez = ex = ey = 0.f;
    if constexpr (BJ >= 3) {
        constexpr int lm = 1 << (BJ - 3);
        const float sgn = (lane & lm) ? -1.f : 1.f;
#pragma unroll
        for (int r = 0; r < 8; ++r) {
            h2 p = i2h(lxi<lm>(h2i(st[r]), lane));
            float x = (float)st[r].x, y = (float)st[r].y;
            float px = (float)p.x,   py = (float)p.y;
            ez += sgn * (x * x + y * y);
            ex += x * px + y * py;            // both halves -> 2*Re total
            ey += sgn * (x * py - y * px);    // both halves -> 2*Im total
        }
    } else {
        constexpr int M = 1 << BJ;
#pragma unroll
        for (int r = 0; r < 8; ++r) {
            if ((r & M) == 0) {
                float ax = (float)st[r].x,     ay = (float)st[r].y;
                float bx = (float)st[r + M].x, by = (float)st[r + M].y;
                ez += (ax * ax + ay * ay) - (bx * bx + by * by);
                ex += 2.f * (ax * bx + ay * by);
                ey += 2.f * (ax * by - ay * bx);
            }
        }
    }
    ez = wave_sum(ez, lane); ex = wave_sum(ex, lane); ey = wave_sum(ey, lane);
}

// ---- Phase A: encoding only, checkpoint to global (8 dwords/lane, coalesced) ----
__global__ __launch_bounds__(64) void enc_kernel(
    const float* __restrict__ inp, int* __restrict__ encOut)
{
    __shared__ int csc[54];
    __shared__ int css[54];

    const int lane = threadIdx.x;
    const int fi   = blockIdx.x;     // flat = s*B + b
    const int b = fi % B_DIM, s = fi / B_DIM;
    const float* x = inp + ((size_t)b * S_DIM + s) * D_DIM;

    if (lane < 54) {
        float ang = x[lane];
        float sn, cn; sincosf(0.5f * ang, &sn, &cn);
        _Float16 hc = (_Float16)cn, hs = (_Float16)sn;
        h2 c2 = {hc, hc}, s2 = {hs, hs};
        csc[lane] = h2i(c2);
        css[lane] = h2i(s2);
    }

    h2 st[8];
#pragma unroll
    for (int r = 0; r < 8; ++r) st[r] = i2h(0);
    if (lane == 0) { h2 one = {(_Float16)1.f, (_Float16)0.f}; st[0] = one; }

    {
        const int* cc = csc; const int* ss = css;
        INITQ(0) INITQ(1) INITQ(2) INITQ(3) INITQ(4)
        INITQ(5) INITQ(6) INITQ(7) INITQ(8)
        const int* pc = csc + 18;
        const int* ps = css + 18;
#pragma unroll 1
        for (int L = 0; L < DENC; ++L) {
            ring(st, lane);
            ry_layer(st, pc, ps, lane);
            pc += 9; ps += 9;
        }
    }

    int* dst = encOut + (size_t)fi * 512;
#pragma unroll
    for (int r = 0; r < 8; ++r)
        dst[r * 64 + lane] = h2i(st[r]);
}

// ---- Phase B: one wave per (input, head). cid 0=Q 1=K 2=V. ----
__global__ __launch_bounds__(64) void var_kernel(
    const int* __restrict__ encIn,
    const float* __restrict__ wq, const float* __restrict__ wk, const float* __restrict__ wv,
    float* __restrict__ outQ, float* __restrict__ outK, float* __restrict__ outV)
{
    __shared__ int csc[90];
    __shared__ int css[90];

    const int lane = threadIdx.x;
    const int gbl  = blockIdx.x;
    const int cid  = gbl % 3;            // 0=Q 1=K 2=V
    const int fi   = gbl / 3;            // flat = s*B + b
    const float* w = (cid == 0) ? wq : (cid == 1) ? wk : wv;

    for (int k = lane; k < 90; k += 64) {
        float ang = w[k];
        float sn, cn; sincosf(0.5f * ang, &sn, &cn);
        _Float16 hc = (_Float16)cn, hs = (_Float16)sn;
        h2 c2 = {hc, hc}, s2 = {hs, hs};
        csc[k] = h2i(c2);
        css[k] = h2i(s2);
    }

    // Load encoding checkpoint (coalesced).
    h2 st[8];
    const int* src = encIn + (size_t)fi * 512;
#pragma unroll
    for (int r = 0; r < 8; ++r)
        st[r] = i2h(src[r * 64 + lane]);

    // Variational circuit: init + (DVAR-1) full layers + final layer.
    {
        const int* cc = csc; const int* ss = css;
        INITQ(0) INITQ(1) INITQ(2) INITQ(3) INITQ(4)
        INITQ(5) INITQ(6) INITQ(7) INITQ(8)
        const int* pc = csc + 18;
        const int* ps = css + 18;
#pragma unroll 1
        for (int L = 0; L < DVAR - 1; ++L) {
            ring(st, lane);
            ry_layer(st, pc, ps, lane);
            pc += 9; ps += 9;
        }
        ring(st, lane);
        if (cid < 2) {
            // Final-layer RYs on qubits 1-8 commute with Z0 — exact trim.
            rot_ry<8>(st, pc[0], ps[0], lane);
        } else {
            ry_layer(st, pc, ps, lane);
        }
    }

    if (cid < 2) {
        float p = 0.f;
#pragma unroll
        for (int r = 0; r < 8; ++r) {
            float xx = (float)st[r].x, yy = (float)st[r].y;
            p += xx * xx + yy * yy;
        }
        p = (lane & 32) ? -p : p;     // qubit 0 = state bit 8 = lane bit 5
        p = wave_sum(p, lane);
        if (lane == 0) { if (cid == 0) outQ[fi] = p; else outK[fi] = p; }
    } else {
        float* vrow = outV + (size_t)fi * D_DIM;
#define EXPQ(q) { float ez, ex, ey; expv<8 - (q)>(st, lane, ez, ex, ey);            \
                  if (lane == 0) { vrow[(q)] = ez; vrow[9 + (q)] = ex;              \
                                   vrow[18 + (q)] = ey; vrow[27 + (q)] = ez;        \
                                   vrow[36 + (q)] = ex; vrow[45 + (q)] = ey; } }
        EXPQ(0) EXPQ(1) EXPQ(2) EXPQ(3) EXPQ(4)
        EXPQ(5) EXPQ(6) EXPQ(7) EXPQ(8)
#undef EXPQ
    }
}

__global__ __launch_bounds__(256) void attn_kernel(
    const float* __restrict__ inp, const float* __restrict__ Q,
    const float* __restrict__ K,   const float* __restrict__ V,
    float* __restrict__ out)
{
    __shared__ float w4[4][S_DIM];
    const int warp = threadIdx.x >> 6;
    const int t    = threadIdx.x & 63;
    const int bi   = blockIdx.x * 4 + warp;   // b*S + i
    const int b    = bi / S_DIM;
    const int i    = bi % S_DIM;
    float* w = w4[warp];

    const float q = Q[i * B_DIM + b];
    float e0, e1 = 0.f;
    {
        float d0 = q - K[t * B_DIM + b];
        e0 = expf(-d0 * d0);
        w[t] = e0;
        if (t < S_DIM - 64) {
            float d1 = q - K[(t + 64) * B_DIM + b];
            e1 = expf(-d1 * d1);
            w[t + 64] = e1;
        }
    }
    float ps = wave_sum(e0 + e1, t);
    const float inv = 1.f / ps;

    if (t < D_DIM) {
        float acc = 0.f;
        for (int j = 0; j < S_DIM; ++j)
            acc += w[j] * V[(size_t)(j * B_DIM + b) * D_DIM + t];
        size_t o = (size_t)bi * D_DIM + t;
        out[o] = inp[o] + acc * inv;
    }
}

extern "C" void kernel_launch(void* const* d_in, const int* in_sizes, int n_in,
                              void* d_out, int out_size, void* d_ws, size_t ws_size,
                              hipStream_t stream)
{
    (void)in_sizes; (void)n_in; (void)out_size; (void)ws_size;
    const float* inp = (const float*)d_in[0];
    const float* wq  = (const float*)d_in[1];
    const float* wk  = (const float*)d_in[2];
    const float* wv  = (const float*)d_in[3];
    float* outp = (float*)d_out;

    float* Qw  = (float*)d_ws;                 // 4608
    float* Kw  = Qw + NFLAT;                   // 4608
    float* Vw  = Kw + NFLAT;                   // 4608*54
    int*   Enc = (int*)(Vw + (size_t)NFLAT * D_DIM);  // 4608*512 ints (9.4 MB)

    enc_kernel<<<NFLAT, 64, 0, stream>>>(inp, Enc);
    var_kernel<<<NFLAT * 3, 64, 0, stream>>>(Enc, wq, wk, wv, Qw, Kw, Vw);
    attn_kernel<<<NFLAT / 4, 256, 0, stream>>>(inp, Qw, Kw, Vw, outp);
}